// Round 9
// baseline (1070.188 us; speedup 1.0000x reference)
//
#include <hip/hip_runtime.h>
#include <hip/hip_cooperative_groups.h>
#include <math.h>

namespace cg = cooperative_groups;

#define DIM 128
#define LN_EPS 1e-5f
#define HB 256     // edge chunks for histogram/scatter passes
#define NSEG 8     // row-segments for expand (HB/NSEG = 32 rows per job)

typedef __attribute__((ext_vector_type(8))) short short8;   // 8 bf16 = 4 VGPR
typedef __attribute__((ext_vector_type(4))) float floatx4;

__device__ __forceinline__ float gelu_exact(float v) {
    return 0.5f * v * (1.0f + erff(v * 0.70710678118654752f));
}
__device__ __forceinline__ float bf2f(unsigned short u) {
    return __uint_as_float(((unsigned)u) << 16);
}
__device__ __forceinline__ short f2bf(float f) {
    unsigned b = __float_as_uint(f);
    return (short)((b + 0x7FFF + ((b >> 16) & 1)) >> 16);  // RNE
}

struct GParams {
    const float *x, *W, *lnw, *lnb, *ew, *bias;
    const int *row, *col;
    unsigned short *h16;
    int *hist, *base, *bktbase;
    int2 *srt;
    float *dinv, *out;
    int n, E, nbkt, nq, chunk;
};

#define SMEM_BYTES 49152   // max over phases (gemm: 32KB swb + 16KB axb)

// ---------------------------------------------------------------------------
// Phase: per-chunk LDS histogram of dest buckets (no global atomics).
// ---------------------------------------------------------------------------
__device__ void phase_hist(char* smem, const GParams& p, int g)
{
    const int tid = threadIdx.x;
    __syncthreads();
    int* lh = (int*)smem;
    for (int b = tid; b < p.nbkt; b += 256) lh[b] = 0;
    __syncthreads();
    int e0 = g * p.chunk;
    int e1 = e0 + p.chunk; if (e1 > p.E) e1 = p.E;
    for (int e = e0 + tid; e < e1; e += 256)
        atomicAdd(&lh[p.col[e] >> 6], 1);
    __syncthreads();
    for (int b = tid; b < p.nbkt; b += 256)
        p.hist[(size_t)g * p.nbkt + b] = lh[b];
}

// ---------------------------------------------------------------------------
// Phase: LN + h = xn@W^T via bf16 MFMA (fragment-order LDS, conflict-free).
// ---------------------------------------------------------------------------
__device__ void phase_gemm(char* smem, const GParams& p, int tile)
{
    const int tid = threadIdx.x;
    short* swb = (short*)smem;             // 2048 frags * 8 bf16 = 32 KB
    short* axb = (short*)(smem + 32768);   // 1024 frags * 8 bf16 = 16 KB
    const int n0 = tile * 64;
    __syncthreads();

    // stage W fragments
    for (int c = tid; c < 2048; c += 256) {
        int nrow = ((c >> 8) << 4) | (c & 15);                    // jt*16+nloc
        int kb   = (((c >> 6) & 3) << 5) + (((c >> 4) & 3) << 3); // kq*32+quad*8
        const float* wp = p.W + nrow * DIM + kb;
        float4 w0 = *(const float4*)wp;
        float4 w1 = *(const float4*)(wp + 4);
        short8 q;
        q[0] = f2bf(w0.x); q[1] = f2bf(w0.y); q[2] = f2bf(w0.z); q[3] = f2bf(w0.w);
        q[4] = f2bf(w1.x); q[5] = f2bf(w1.y); q[6] = f2bf(w1.z); q[7] = f2bf(w1.w);
        *(short8*)&swb[c * 8] = q;
    }

    // LayerNorm straight from global, 4 threads/node
    {
        int m = tid >> 2, sub = tid & 3;
        int node = n0 + m;
        bool valid = (node < p.n);
        const float4* xp = (const float4*)(p.x + (size_t)node * DIM + sub * 32);
        float4 v[8];
        float s = 0.f, ss = 0.f;
        #pragma unroll
        for (int i = 0; i < 8; ++i) {
            v[i] = valid ? xp[i] : make_float4(0.f, 0.f, 0.f, 0.f);
            s  += v[i].x + v[i].y + v[i].z + v[i].w;
            ss += v[i].x * v[i].x + v[i].y * v[i].y + v[i].z * v[i].z + v[i].w * v[i].w;
        }
        s += __shfl_xor(s, 1); ss += __shfl_xor(ss, 1);
        s += __shfl_xor(s, 2); ss += __shfl_xor(ss, 2);
        float mu   = s * (1.0f / 128.0f);
        float var  = ss * (1.0f / 128.0f) - mu * mu;
        float rstd = rsqrtf(var + LN_EPS);

        int mt = m >> 4, mloc = m & 15;
        #pragma unroll
        for (int quad = 0; quad < 4; ++quad) {
            float4 a = v[2 * quad], c4 = v[2 * quad + 1];
            const float4* lw = (const float4*)(p.lnw + sub * 32 + quad * 8);
            const float4* lb = (const float4*)(p.lnb + sub * 32 + quad * 8);
            float4 lw0 = lw[0], lw1 = lw[1], lb0 = lb[0], lb1 = lb[1];
            short8 q;
            q[0] = f2bf((a.x  - mu) * rstd * lw0.x + lb0.x);
            q[1] = f2bf((a.y  - mu) * rstd * lw0.y + lb0.y);
            q[2] = f2bf((a.z  - mu) * rstd * lw0.z + lb0.z);
            q[3] = f2bf((a.w  - mu) * rstd * lw0.w + lb0.w);
            q[4] = f2bf((c4.x - mu) * rstd * lw1.x + lb1.x);
            q[5] = f2bf((c4.y - mu) * rstd * lw1.y + lb1.y);
            q[6] = f2bf((c4.z - mu) * rstd * lw1.z + lb1.z);
            q[7] = f2bf((c4.w - mu) * rstd * lw1.w + lb1.w);
            int slot = mt * 256 + sub * 64 + quad * 16 + mloc;
            *(short8*)&axb[slot * 8] = q;
        }
    }
    __syncthreads();

    const int w    = tid >> 6;
    const int lane = tid & 63;

    short8 afrag[4];
    #pragma unroll
    for (int kq = 0; kq < 4; ++kq)
        afrag[kq] = *(const short8*)&axb[(w * 256 + kq * 64 + lane) * 8];

    floatx4 acc[8];
    #pragma unroll
    for (int jt = 0; jt < 8; ++jt) acc[jt] = (floatx4){0.f, 0.f, 0.f, 0.f};

    #pragma unroll
    for (int jt = 0; jt < 8; ++jt) {
        #pragma unroll
        for (int kq = 0; kq < 4; ++kq) {
            short8 bfrag = *(const short8*)&swb[(jt * 256 + kq * 64 + lane) * 8];
            acc[jt] = __builtin_amdgcn_mfma_f32_16x16x32_bf16(afrag[kq], bfrag,
                                                              acc[jt], 0, 0, 0);
        }
    }

    const int quad = lane >> 4, nl = lane & 15;
    #pragma unroll
    for (int jt = 0; jt < 8; ++jt) {
        #pragma unroll
        for (int r = 0; r < 4; ++r) {
            int rnode = n0 + w * 16 + quad * 4 + r;
            if (rnode < p.n)
                p.h16[(size_t)rnode * DIM + jt * 16 + nl] =
                    (unsigned short)f2bf(acc[jt][r]);
        }
    }
}

// ---------------------------------------------------------------------------
// Phase: expand. Job (s,q): recompute bucket totals for all nq slices (strided
// but latency-parallel), block-scan -> global bucket offsets, then write the
// per-(chunk,bucket) base matrix for rows [s*32, s*32+32).
// ---------------------------------------------------------------------------
__device__ void phase_expand(char* smem, const GParams& p, int job)
{
    const int tid = threadIdx.x;
    int* ls = (int*)smem;
    const int s  = job / p.nq;
    const int q  = job % p.nq;
    const int g0 = s * (HB / NSEG);
    __syncthreads();

    int tq[8];
    int pref = 0;
    for (int qq = 0; qq < p.nq; ++qq) {
        int bq = qq * 256 + tid;
        int t = 0;
        if (bq < p.nbkt) {
            const int* hp = p.hist + bq;
            if (qq == q) {
                #pragma unroll 4
                for (int g = 0; g < HB; ++g) {
                    int v = hp[(size_t)g * p.nbkt];
                    t += v;
                    if (g < g0) pref += v;
                }
            } else {
                #pragma unroll 4
                for (int g = 0; g < HB; ++g)
                    t += hp[(size_t)g * p.nbkt];
            }
        }
        tq[qq] = t;
    }

    int carry = 0, excl_mine = 0;
    for (int qq = 0; qq < p.nq; ++qq) {
        int v = tq[qq];
        __syncthreads();
        ls[tid] = v;
        __syncthreads();
        int inc = v;
        for (int off = 1; off < 256; off <<= 1) {
            int add = (tid >= off) ? ls[tid - off] : 0;
            __syncthreads();
            inc += add;
            ls[tid] = inc;
            __syncthreads();
        }
        int ex = carry + inc - v;
        if (qq == q) {
            excl_mine = ex;
            int b = q * 256 + tid;
            if (s == 0 && b < p.nbkt) p.bktbase[b] = ex;
        }
        carry += ls[255];
    }
    if (s == 0 && q == 0 && tid == 0) p.bktbase[p.nbkt] = p.E;

    int b = q * 256 + tid;
    if (b < p.nbkt) {
        int run = excl_mine + pref;
        for (int g = g0; g < g0 + HB / NSEG; ++g) {
            size_t idx = (size_t)g * p.nbkt + b;
            p.base[idx] = run;
            run += p.hist[idx];
        }
    }
}

// ---------------------------------------------------------------------------
// Phase: scatter edges into bucket order via LDS cursors.
// srt entry: ((dest & 63) << 16) | src   (requires n <= 65536), ew bits.
// ---------------------------------------------------------------------------
__device__ void phase_scatter(char* smem, const GParams& p, int g)
{
    const int tid = threadIdx.x;
    int* cur = (int*)smem;
    __syncthreads();
    for (int b = tid; b < p.nbkt; b += 256)
        cur[b] = p.base[(size_t)g * p.nbkt + b];
    __syncthreads();
    int e0 = g * p.chunk;
    int e1 = e0 + p.chunk; if (e1 > p.E) e1 = p.E;
    for (int e = e0 + tid; e < e1; e += 256) {
        int c = p.col[e];
        int pos = atomicAdd(&cur[c >> 6], 1);
        p.srt[pos] = make_int2(((c & 63) << 16) | p.row[e],
                               __float_as_int(p.ew[e]));
    }
}

// ---------------------------------------------------------------------------
// Phase: dinv. Block per bucket: deg = 1 + sum(ew) over srt segment.
// ---------------------------------------------------------------------------
__device__ void phase_dinv(char* smem, const GParams& p, int b)
{
    const int tid = threadIdx.x;
    float* w64 = (float*)smem;
    __syncthreads();
    if (tid < 64) w64[tid] = 0.f;
    __syncthreads();
    int s0 = p.bktbase[b], s1 = p.bktbase[b + 1];
    for (int i = s0 + tid; i < s1; i += 256) {
        int2 v = p.srt[i];
        atomicAdd(&w64[(v.x >> 16) & 63], __int_as_float(v.y));
    }
    __syncthreads();
    int dest = b * 64 + tid;
    if (tid < 64 && dest < p.n)
        p.dinv[dest] = rsqrtf(1.0f + w64[tid]);
}

// ---------------------------------------------------------------------------
// Phase: gather. Block per bucket: 64x128 fp32 LDS accumulator (stride 132),
// edges streamed in 256-chunks; per edge 16 lanes x 8 dims, ds_add_f32.
// Epilogue: out = gelu(dv*acc + dv^2*h_self + bias).
// ---------------------------------------------------------------------------
__device__ void phase_gather(char* smem, const GParams& p, int b)
{
    const int tid = threadIdx.x;
    float* acc = (float*)smem;                     // 64*132 = 33792 B
    int2*  ebuf = (int2*)(smem + 64 * 132 * 4);    // 256 int2 = 2 KB
    __syncthreads();
    for (int i = tid; i < 64 * 132; i += 256) acc[i] = 0.f;

    int s0 = p.bktbase[b], s1 = p.bktbase[b + 1];
    const int w   = tid >> 6;
    const int q   = (tid >> 4) & 3;
    const int sub = tid & 15;

    for (int ch = s0; ch < s1; ch += 256) {
        int cnt = s1 - ch; if (cnt > 256) cnt = 256;
        __syncthreads();
        if (tid < cnt) ebuf[tid] = p.srt[ch + tid];
        __syncthreads();
        #pragma unroll 2
        for (int i = 0; i < 16; ++i) {
            int ei = w * 64 + i * 4 + q;
            if (ei < cnt) {
                int2 v = ebuf[ei];
                int src = v.x & 0xFFFF;
                int d   = (v.x >> 16) & 63;
                float nr = p.dinv[src] * __int_as_float(v.y);
                short8 h = *(const short8*)(p.h16 + (size_t)src * DIM + sub * 8);
                float* ap = acc + d * 132 + sub * 8;
                #pragma unroll
                for (int k = 0; k < 8; ++k)
                    atomicAdd(&ap[k], nr * bf2f((unsigned short)h[k]));
            }
        }
    }
    __syncthreads();

    // epilogue: thread = (d = tid>>2, part = tid&3) -> dims part*32..part*32+31
    int d = tid >> 2, part = tid & 3;
    int dest = b * 64 + d;
    if (dest < p.n) {
        float dv = p.dinv[dest], s2 = dv * dv;
        const unsigned short* hs = p.h16 + (size_t)dest * DIM + part * 32;
        const float* ap = acc + d * 132 + part * 32;
        const float* bp = p.bias + part * 32;
        float* op = p.out + (size_t)dest * DIM + part * 32;
        #pragma unroll
        for (int j = 0; j < 4; ++j) {
            short8 hv = *(const short8*)(hs + j * 8);
            float4 a0 = *(const float4*)(ap + j * 8);
            float4 a1 = *(const float4*)(ap + j * 8 + 4);
            float4 b0 = *(const float4*)(bp + j * 8);
            float4 b1 = *(const float4*)(bp + j * 8 + 4);
            float4 o0, o1;
            o0.x = gelu_exact(dv * a0.x + s2 * bf2f((unsigned short)hv[0]) + b0.x);
            o0.y = gelu_exact(dv * a0.y + s2 * bf2f((unsigned short)hv[1]) + b0.y);
            o0.z = gelu_exact(dv * a0.z + s2 * bf2f((unsigned short)hv[2]) + b0.z);
            o0.w = gelu_exact(dv * a0.w + s2 * bf2f((unsigned short)hv[3]) + b0.w);
            o1.x = gelu_exact(dv * a1.x + s2 * bf2f((unsigned short)hv[4]) + b1.x);
            o1.y = gelu_exact(dv * a1.y + s2 * bf2f((unsigned short)hv[5]) + b1.y);
            o1.z = gelu_exact(dv * a1.z + s2 * bf2f((unsigned short)hv[6]) + b1.z);
            o1.w = gelu_exact(dv * a1.w + s2 * bf2f((unsigned short)hv[7]) + b1.w);
            *(float4*)(op + j * 8)     = o0;
            *(float4*)(op + j * 8 + 4) = o1;
        }
    }
}

// ---------------------------------------------------------------------------
// Mega cooperative kernel: 5 phases, 4 grid syncs, 1 dispatch.
// ---------------------------------------------------------------------------
__global__ __launch_bounds__(256) void mega_kernel(GParams p)
{
    __shared__ longlong2 smem_ll[SMEM_BYTES / 16];
    char* smem = (char*)smem_ll;
    cg::grid_group grid = cg::this_grid();
    const int bid = blockIdx.x, g = gridDim.x;

    for (int job = bid; job < HB + p.nbkt; job += g) {
        if (job < HB) phase_hist(smem, p, job);
        else          phase_gemm(smem, p, job - HB);
    }
    grid.sync();
    for (int job = bid; job < NSEG * p.nq; job += g) phase_expand(smem, p, job);
    grid.sync();
    for (int job = bid; job < HB; job += g) phase_scatter(smem, p, job);
    grid.sync();
    for (int job = bid; job < p.nbkt; job += g) phase_dinv(smem, p, job);
    grid.sync();
    for (int job = bid; job < p.nbkt; job += g) phase_gather(smem, p, job);
}

// ---------------------------------------------------------------------------
// Fallback wrappers (if cooperative launch is unavailable): same phases,
// 5 separate dispatches.
// ---------------------------------------------------------------------------
__global__ __launch_bounds__(256) void k_gemm_hist(GParams p) {
    __shared__ longlong2 smem_ll[SMEM_BYTES / 16];
    char* smem = (char*)smem_ll;
    if ((int)blockIdx.x < HB) phase_hist(smem, p, blockIdx.x);
    else                      phase_gemm(smem, p, blockIdx.x - HB);
}
__global__ __launch_bounds__(256) void k_expand(GParams p) {
    __shared__ longlong2 smem_ll[64];    // 1 KB
    phase_expand((char*)smem_ll, p, blockIdx.x);
}
__global__ __launch_bounds__(256) void k_scatter(GParams p) {
    __shared__ longlong2 smem_ll[256];   // 4 KB
    phase_scatter((char*)smem_ll, p, blockIdx.x);
}
__global__ __launch_bounds__(256) void k_dinv(GParams p) {
    __shared__ longlong2 smem_ll[16];    // 256 B
    phase_dinv((char*)smem_ll, p, blockIdx.x);
}
__global__ __launch_bounds__(256) void k_gather(GParams p) {
    __shared__ longlong2 smem_ll[2256];  // 36 KB
    phase_gather((char*)smem_ll, p, blockIdx.x);
}

extern "C" void kernel_launch(void* const* d_in, const int* in_sizes, int n_in,
                              void* d_out, int out_size, void* d_ws, size_t ws_size,
                              hipStream_t stream)
{
    const int n = in_sizes[0] / DIM;
    const int E = in_sizes[2];
    const int nbkt = (n + 63) / 64;

    GParams p;
    p.x    = (const float*)d_in[0];
    p.row  = (const int*)d_in[1];          // sources
    p.col  = ((const int*)d_in[1]) + E;    // targets
    p.ew   = (const float*)d_in[2];
    p.W    = (const float*)d_in[3];
    p.bias = (const float*)d_in[4];
    p.lnw  = (const float*)d_in[5];
    p.lnb  = (const float*)d_in[6];
    p.out  = (float*)d_out;
    p.n = n; p.E = E; p.nbkt = nbkt;
    p.nq = (nbkt + 255) / 256;
    p.chunk = (E + HB - 1) / HB;

    // workspace layout (8B-aligned first)
    p.srt     = (int2*)d_ws;                                  // E int2
    p.h16     = (unsigned short*)(p.srt + E);                 // n*128
    p.hist    = (int*)(p.h16 + (size_t)n * DIM);              // HB*nbkt
    p.base    = p.hist + (size_t)HB * nbkt;                   // HB*nbkt
    p.bktbase = p.base + (size_t)HB * nbkt;                   // nbkt+1
    p.dinv    = (float*)(p.bktbase + nbkt + 1);               // n
    // total ~21.3 MB

    // cooperative path
    int nbpc = 0;
    hipError_t qerr = hipOccupancyMaxActiveBlocksPerMultiprocessor(
        &nbpc, mega_kernel, 256, 0);
    int dev = 0, cus = 0;
    hipGetDevice(&dev);
    hipDeviceGetAttribute(&cus, hipDeviceAttributeMultiprocessorCount, dev);
    if (cus <= 0) cus = 256;

    if (qerr == hipSuccess && nbpc >= 1) {
        int grid = nbpc * cus;
        int maxjobs = HB + nbkt;
        if (grid > maxjobs) grid = maxjobs;
        void* kargs[] = {(void*)&p};
        hipError_t err = hipLaunchCooperativeKernel(
            mega_kernel, dim3(grid), dim3(256), kargs, 0, stream);
        if (err == hipSuccess) return;
        (void)hipGetLastError();   // clear and fall through
    }

    // fallback: 5 separate dispatches of the same phases
    k_gemm_hist<<<HB + nbkt, 256, 0, stream>>>(p);
    k_expand<<<NSEG * p.nq, 256, 0, stream>>>(p);
    k_scatter<<<HB, 256, 0, stream>>>(p);
    k_dinv<<<nbkt, 256, 0, stream>>>(p);
    k_gather<<<nbkt, 256, 0, stream>>>(p);
}